// Round 8
// baseline (7844.253 us; speedup 1.0000x reference)
//
#include <hip/hip_runtime.h>
#include <hip/hip_bf16.h>

#define B_  32
#define A_  128
#define T_  64
#define N_  4096        // B_*A_
#define HS  256
#define ES  32
#define RS  64
#define KX  832         // 64 (r) + 512 (e) + 256 (h)
#define GD  1024        // 4*HS
#define NKT 26          // KX/32

typedef __attribute__((ext_vector_type(8))) short bf8_t;            // 8 x bf16
typedef __attribute__((ext_vector_type(8))) unsigned short u16x8;
typedef __attribute__((ext_vector_type(4))) float f4_t;             // mfma acc
typedef __attribute__((ext_vector_type(2))) float f2_t;

__device__ __forceinline__ unsigned short f2bf(float x) {
  union { float f; unsigned u; } v; v.f = x;
  unsigned u = v.u;
  u += 0x7fffu + ((u >> 16) & 1u);     // round-to-nearest-even
  return (unsigned short)(u >> 16);
}
__device__ __forceinline__ float bf2f(unsigned short u) {
  union { unsigned u; float f; } v; v.u = ((unsigned)u) << 16; return v.f;
}
__device__ __forceinline__ float sigm(float x) { return 1.f / (1.f + __expf(-x)); }

__device__ __forceinline__ void gload16(const void* g, void* l) {
  __builtin_amdgcn_global_load_lds((const __attribute__((address_space(1))) void*)g,
                                   (__attribute__((address_space(3))) void*)l, 16, 0, 0);
}

// 16-block per-batch sense-reversing barrier (device scope).
__device__ __forceinline__ void batch_barrier(int* cnt, int* gen) {
  __syncthreads();                      // drains vmcnt: block's writes issued
  if (threadIdx.x == 0) {
    int g = __hip_atomic_load(gen, __ATOMIC_RELAXED, __HIP_MEMORY_SCOPE_AGENT);
    __threadfence();                    // agent-scope release of our data
    int old = __hip_atomic_fetch_add(cnt, 1, __ATOMIC_ACQ_REL, __HIP_MEMORY_SCOPE_AGENT);
    if (old == 15) {
      __hip_atomic_store(cnt, 0, __ATOMIC_RELAXED, __HIP_MEMORY_SCOPE_AGENT);
      __hip_atomic_fetch_add(gen, 1, __ATOMIC_RELEASE, __HIP_MEMORY_SCOPE_AGENT);
    } else {
      while (__hip_atomic_load(gen, __ATOMIC_ACQUIRE, __HIP_MEMORY_SCOPE_AGENT) == g)
        __builtin_amdgcn_s_sleep(4);
    }
    __threadfence();                    // acquire side
  }
  __syncthreads();
}

// ---- Wc (permuted) + fused bias + bf16 W_e copy
__global__ void k_wcat(const float* __restrict__ W_ih, const float* __restrict__ W_hh,
                       const float* __restrict__ b_ih, const float* __restrict__ b_hh,
                       const float* __restrict__ W_e,
                       unsigned short* __restrict__ Wc, float* __restrict__ bsum,
                       unsigned short* __restrict__ Web) {
  int i = blockIdx.x * 256 + threadIdx.x;
  if (i < GD * KX) {
    int mp = i / KX, k = i - mp * KX;
    int nb = mp >> 6, rem = mp & 63, g = rem >> 4, q = rem & 15;
    int mo = g * 256 + nb * 16 + q;
    float v = (k < 576) ? W_ih[mo * 576 + k] : W_hh[mo * 256 + (k - 576)];
    Wc[i] = f2bf(v);
  } else if (i < GD * KX + GD) {
    int j = i - GD * KX;
    int nb = j >> 6, rem = j & 63, g = rem >> 4, q = rem & 15;
    int mo = g * 256 + nb * 16 + q;
    bsum[j] = b_ih[mo] + b_hh[mo];
  } else if (i < GD * KX + GD + ES * HS) {
    int j2 = i - GD * KX - GD;
    Web[j2] = f2bf(W_e[j2]);
  }
}

// ---- collapsed head: Whead[o][320] = (Wo @ W_p2) @ W_p   (5 blocks x 320 thr)
__global__ __launch_bounds__(320) void k_head(
    const float* __restrict__ W_p, const float* __restrict__ b_p,
    const float* __restrict__ W_p2, const float* __restrict__ b_p2,
    const float* __restrict__ W_mu, const float* __restrict__ b_mu,
    const float* __restrict__ W_sd, const float* __restrict__ b_sd,
    const float* __restrict__ W_cr, const float* __restrict__ b_cr,
    float* __restrict__ Whead, float* __restrict__ bhead) {
  int o = blockIdx.x, tid = threadIdx.x;
  __shared__ float to[64];
  const float* Wo = (o < 2) ? W_mu + o * 32 : (o < 4) ? W_sd + (o - 2) * 32 : W_cr;
  if (tid < 64) {
    float a = 0.f;
    #pragma unroll 8
    for (int c = 0; c < 32; ++c) a += Wo[c] * W_p2[c * 64 + tid];
    to[tid] = a;
  }
  __syncthreads();
  float a = 0.f;
  #pragma unroll 8
  for (int j = 0; j < 64; ++j) a += to[j] * W_p[j * 320 + tid];
  Whead[o * 320 + tid] = a;
  if (tid == 0) {
    float b0 = (o < 2) ? b_mu[o] : (o < 4) ? b_sd[o - 2] : b_cr[0];
    float acc = b0;
    for (int c = 0; c < 32; ++c) acc += Wo[c] * b_p2[c];
    for (int j = 0; j < 64; ++j) acc += to[j] * b_p[j];
    bhead[o] = acc;
  }
}

// ---- head for step ts, rows n0..n0+8. h2(ts) is the bf16 h-part of Xh.
__device__ __forceinline__ void head_fin_dev(
    const float* __restrict__ data, const float* __restrict__ W_r,
    const float* __restrict__ b_r, const float* __restrict__ Whead,
    const float* __restrict__ bhead, const unsigned short* __restrict__ Xh,
    float* __restrict__ out, int n0, int ts, int tid) {
  int r8 = tid >> 5, ln = tid & 31;
  int n = n0 + r8;
  float s0 = 0.f, s1 = 0.f, s2 = 0.f, s3 = 0.f, s4 = 0.f;
  u16x8 hv = *(const u16x8*)(Xh + (size_t)n * KX + 576 + ln * 8);
  float hf[8];
  #pragma unroll
  for (int k = 0; k < 8; ++k) hf[k] = bf2f(hv[k]);
  #pragma unroll
  for (int k = 0; k < 8; ++k) {
    int kk = 64 + ln * 8 + k;
    s0 += hf[k] * Whead[0 * 320 + kk];
    s1 += hf[k] * Whead[1 * 320 + kk];
    s2 += hf[k] * Whead[2 * 320 + kk];
    s3 += hf[k] * Whead[3 * 320 + kk];
    s4 += hf[k] * Whead[4 * 320 + kk];
  }
  float x0 = data[(n * T_ + ts) * 2 + 0];
  float x1 = data[(n * T_ + ts) * 2 + 1];
  #pragma unroll
  for (int l2 = 0; l2 < 2; ++l2) {
    int l = ln + 32 * l2;
    float rv = fmaxf(x0 * W_r[l * 2] + x1 * W_r[l * 2 + 1] + b_r[l], 0.f);
    s0 += rv * Whead[0 * 320 + l];
    s1 += rv * Whead[1 * 320 + l];
    s2 += rv * Whead[2 * 320 + l];
    s3 += rv * Whead[3 * 320 + l];
    s4 += rv * Whead[4 * 320 + l];
  }
  #pragma unroll
  for (int off = 16; off; off >>= 1) {
    s0 += __shfl_xor(s0, off);
    s1 += __shfl_xor(s1, off);
    s2 += __shfl_xor(s2, off);
    s3 += __shfl_xor(s3, off);
    s4 += __shfl_xor(s4, off);
  }
  if (ln == 0) {
    out[(n * T_ + ts) * 2 + 0] = s0 + bhead[0];
    out[(n * T_ + ts) * 2 + 1] = s1 + bhead[1];
    out[N_ * T_ * 2 + (n * T_ + ts) * 2 + 0] = __expf(s2 + bhead[2]);
    out[N_ * T_ * 2 + (n * T_ + ts) * 2 + 1] = __expf(s3 + bhead[3]);
    out[N_ * T_ * 4 + n * T_ + ts] = tanhf(s4 + bhead[4]);
  }
}

// ---- persistent kernel: whole T loop. 512 blocks = 32 batches x 16 roles.
// Per t: [social, role=row-group ig] -> batch barrier -> [gemm, role=col-tile tn]
// -> batch barrier. Batch's 16 blocks co-located per XCD via bid&7 mapping.
__global__ __launch_bounds__(256, 2) void k_persist(
    const float* __restrict__ data, const unsigned short* __restrict__ Web,
    const float* __restrict__ b_e, const float* __restrict__ Whead,
    const float* __restrict__ bhead, const float* __restrict__ W_r,
    const float* __restrict__ b_r, const unsigned short* __restrict__ Wc,
    const float* __restrict__ bsum, float* __restrict__ cbuf,
    unsigned short* __restrict__ X0, unsigned short* __restrict__ X1,
    int* __restrict__ bar, float* __restrict__ out) {
  __shared__ __align__(16) char smem[50176];
  __shared__ float sbias[64];
  int bid = blockIdx.x;
  int xcd = bid & 7, slot = bid >> 3;
  int b = xcd + 8 * (slot >> 4);       // batch 0..31
  int role = slot & 15;                // ig (social) / tn (gemm)
  int tid = threadIdx.x;
  int* cnt = bar + b * 64;
  int* gen = cnt + 16;

  // phase-S views
  float* sx   = (float*)smem;                       // 128
  float* sy   = (float*)(smem + 512);               // 128
  float* shw2 = (float*)(smem + 1024);              // 4096  [jp][c][sub]
  float* smxp = (float*)(smem + 17408);             // [r][jp][8]
  float* smyp = (float*)(smem + 33792);             // [r][jp][8]
  // phase-G views
  unsigned short* sA0 = (unsigned short*)smem;
  unsigned short* sB0 = (unsigned short*)(smem + 8192);
  unsigned short* sA1 = (unsigned short*)(smem + 12288);
  unsigned short* sB1 = (unsigned short*)(smem + 20480);
  float (*gtile)[65] = (float (*)[65])smem;

  if (tid < 64) sbias[tid] = bsum[role * 64 + tid];

  int n0 = b * A_ + role * 8;
  int lane = tid & 63;
  int w = tid >> 6;

  for (int t = 0; t < T_; ++t) {
    unsigned short* Xcur  = (t & 1) ? X1 : X0;
    unsigned short* Xnext = (t & 1) ? X0 : X1;

    // ================= phase S (role = ig) =================
    if (tid < A_) {
      sx[tid] = data[((b * A_ + tid) * T_ + t) * 2 + 0];
      sy[tid] = data[((b * A_ + tid) * T_ + t) * 2 + 1];
    }
    if (t > 0)
      head_fin_dev(data, W_r, b_r, Whead, bhead, Xcur, out, n0, t - 1, tid);
    for (int u = tid; u < 512; u += 256) {
      int rr = u >> 6, l = u & 63;
      int n = n0 + rr;
      float x0 = data[(n * T_ + t) * 2 + 0];
      float x1 = data[(n * T_ + t) * 2 + 1];
      Xcur[(size_t)n * KX + l] =
          f2bf(fmaxf(x0 * W_r[l * 2] + x1 * W_r[l * 2 + 1] + b_r[l], 0.f));
    }
    // hW = h2 @ W_e^T via MFMA (redundant per block; L2-hot)
    {
      int lr = lane & 15, lh = lane >> 4;
      const unsigned short* a0p = Xcur + (size_t)(b * A_ + w * 32 + lr) * KX + 576 + lh * 8;
      const unsigned short* a1p = a0p + 16 * KX;
      const unsigned short* b0p = Web + lr * HS + lh * 8;
      const unsigned short* b1p = Web + (16 + lr) * HS + lh * 8;
      f4_t hacc[2][2];
      hacc[0][0] = (f4_t){0.f,0.f,0.f,0.f}; hacc[0][1] = hacc[0][0];
      hacc[1][0] = hacc[0][0];              hacc[1][1] = hacc[0][0];
      #pragma unroll
      for (int kk = 0; kk < 8; ++kk) {
        bf8_t av0 = *(const bf8_t*)(a0p + kk * 32);
        bf8_t av1 = *(const bf8_t*)(a1p + kk * 32);
        bf8_t bv0 = *(const bf8_t*)(b0p + kk * 32);
        bf8_t bv1 = *(const bf8_t*)(b1p + kk * 32);
        hacc[0][0] = __builtin_amdgcn_mfma_f32_16x16x32_bf16(av0, bv0, hacc[0][0], 0, 0, 0);
        hacc[0][1] = __builtin_amdgcn_mfma_f32_16x16x32_bf16(av0, bv1, hacc[0][1], 0, 0, 0);
        hacc[1][0] = __builtin_amdgcn_mfma_f32_16x16x32_bf16(av1, bv0, hacc[1][0], 0, 0, 0);
        hacc[1][1] = __builtin_amdgcn_mfma_f32_16x16x32_bf16(av1, bv1, hacc[1][1], 0, 0, 0);
      }
      int ccol = lane & 15, crow4 = (lane >> 4) * 4;
      #pragma unroll
      for (int m = 0; m < 2; ++m)
        #pragma unroll
        for (int cb2 = 0; cb2 < 2; ++cb2)
          #pragma unroll
          for (int j = 0; j < 4; ++j) {
            int rr = w * 32 + m * 16 + crow4 + j;
            int c  = cb2 * 16 + ccol;
            shw2[(rr >> 1) * 64 + c * 2 + (rr & 1)] = hacc[m][cb2][j];
          }
    }
    __syncthreads();

    // phase 1: indicators
    for (int u = tid; u < 512; u += 256) {
      int r = u >> 6, jp = u & 63;
      int irow = role * 8 + r;
      float xi = sx[irow], yi = sy[irow];
      bool acti = xi >= 0.f;
      float m0[4], m1[4], nn0[4], nn1[4];
      #pragma unroll
      for (int s = 0; s < 2; ++s) {
        int j = jp * 2 + s;
        float xj = sx[j], yj = sy[j];
        bool v = acti && (xj >= 0.f) && (j != irow);
        float dx = xi - xj, dy = yi - yj;
        float* mm = s ? m1 : m0;
        float* nn = s ? nn1 : nn0;
        mm[0] = (v && dx >= 8.f   && dx <= 16.f) ? 1.f : 0.f;
        mm[1] = (v && dx >= 0.f   && dx <= 8.f ) ? 1.f : 0.f;
        mm[2] = (v && dx >= -8.f  && dx <= 0.f ) ? 1.f : 0.f;
        mm[3] = (v && dx >= -16.f && dx <= -8.f) ? 1.f : 0.f;
        nn[0] = (dy >= -16.f && dy <= -8.f) ? 1.f : 0.f;
        nn[1] = (dy >= -8.f  && dy <= 0.f ) ? 1.f : 0.f;
        nn[2] = (dy >= 0.f   && dy <= 8.f ) ? 1.f : 0.f;
        nn[3] = (dy >= 8.f   && dy <= 16.f) ? 1.f : 0.f;
      }
      float4* px = (float4*)&smxp[(r * 64 + jp) * 8];
      px[0] = (float4){m0[0], m1[0], m0[1], m1[1]};
      px[1] = (float4){m0[2], m1[2], m0[3], m1[3]};
      float4* py = (float4*)&smyp[(r * 64 + jp) * 8];
      py[0] = (float4){nn0[0], nn1[0], nn0[1], nn1[1]};
      py[1] = (float4){nn0[2], nn1[2], nn0[3], nn1[3]};
    }
    __syncthreads();

    // phase 2: register accumulate
    {
      int half = tid >> 5;
      int ch = tid & 31;
      f2_t acc[16];
      #pragma unroll
      for (int g = 0; g < 16; ++g) acc[g] = (f2_t){0.f, 0.f};
      #pragma unroll 2
      for (int jp = 0; jp < 64; ++jp) {
        f2_t hv = *(const f2_t*)&shw2[jp * 64 + ch * 2];
        float4 xa = ((const float4*)&smxp[(half * 64 + jp) * 8])[0];
        float4 xb = ((const float4*)&smxp[(half * 64 + jp) * 8])[1];
        float4 ya = ((const float4*)&smyp[(half * 64 + jp) * 8])[0];
        float4 yb = ((const float4*)&smyp[(half * 64 + jp) * 8])[1];
        f2_t mx[4] = {(f2_t){xa.x, xa.y}, (f2_t){xa.z, xa.w},
                      (f2_t){xb.x, xb.y}, (f2_t){xb.z, xb.w}};
        f2_t p[4]  = {(f2_t){ya.x, ya.y} * hv, (f2_t){ya.z, ya.w} * hv,
                      (f2_t){yb.x, yb.y} * hv, (f2_t){yb.z, yb.w} * hv};
        #pragma unroll
        for (int gy = 0; gy < 4; ++gy)
          #pragma unroll
          for (int gx = 0; gx < 4; ++gx)
            acc[gy * 4 + gx] += mx[gx] * p[gy];
      }
      int irow = role * 8 + half;
      float be = b_e[ch];
      int hi = irow >> 4;
      int klo = (irow & 15) * ES + ch;
      #pragma unroll
      for (int g = 0; g < 16; ++g) {
        float e = fmaxf(acc[g][0] + acc[g][1] + be, 0.f);
        int a_out = g * 8 + hi;
        Xcur[(size_t)(b * A_ + a_out) * KX + 64 + klo] = f2bf(e);
      }
    }

    batch_barrier(cnt, gen);

    // ================= phase G (role = tn) =================
    {
      int row0 = b * A_, col0 = role * 64;
      int wr = w >> 1, wc2 = w & 1;
      int lr = lane & 15, lh = lane >> 4;
      int srow = tid >> 2, schunk = tid & 3;
      int gch = (schunk ^ ((srow >> 1) & 3)) * 8;
      const unsigned short* gA0 = Xcur + (size_t)(row0 + srow) * KX + gch;
      const unsigned short* gA1 = Xcur + (size_t)(row0 + 64 + srow) * KX + gch;
      const unsigned short* gB  = Wc  + (size_t)(col0 + srow) * KX + gch;
      int swz = (lh ^ ((lr >> 1) & 3)) * 8;
      int aoff[4], boff[2];
      #pragma unroll
      for (int m = 0; m < 4; ++m) aoff[m] = (wr * 64 + m * 16 + lr) * 32 + swz;
      #pragma unroll
      for (int n = 0; n < 2; ++n) boff[n] = (wc2 * 32 + n * 16 + lr) * 32 + swz;

      f4_t acc[4][2];
      #pragma unroll
      for (int m = 0; m < 4; ++m)
        #pragma unroll
        for (int n = 0; n < 2; ++n) acc[m][n] = (f4_t){0.f, 0.f, 0.f, 0.f};

#define STAGE(pA, pB, kt) do { \
      gload16(gA0 + (kt) * 32, (pA) + tid * 8); \
      gload16(gA1 + (kt) * 32, (pA) + 2048 + tid * 8); \
      gload16(gB  + (kt) * 32, (pB) + tid * 8); \
    } while (0)
#define COMPUTE(pA, pB) do { \
      bf8_t a_[4], b_[2]; \
      _Pragma("unroll") for (int m = 0; m < 4; ++m) a_[m] = *(const bf8_t*)((pA) + aoff[m]); \
      _Pragma("unroll") for (int n = 0; n < 2; ++n) b_[n] = *(const bf8_t*)((pB) + boff[n]); \
      _Pragma("unroll") for (int m = 0; m < 4; ++m) \
        _Pragma("unroll") for (int n = 0; n < 2; ++n) \
          acc[m][n] = __builtin_amdgcn_mfma_f32_16x16x32_bf16(a_[m], b_[n], acc[m][n], 0, 0, 0); \
    } while (0)

      STAGE(sA0, sB0, 0);
      __syncthreads();
      #pragma unroll 1
      for (int kt = 0; kt < NKT; kt += 2) {
        STAGE(sA1, sB1, kt + 1);
        COMPUTE(sA0, sB0);
        __syncthreads();
        if (kt + 2 < NKT) STAGE(sA0, sB0, kt + 2);
        COMPUTE(sA1, sB1);
        __syncthreads();
      }
#undef STAGE
#undef COMPUTE

      int crow = (lane >> 4) * 4, ccol = lane & 15;
      #pragma unroll
      for (int m = 0; m < 4; ++m)
        #pragma unroll
        for (int n = 0; n < 2; ++n)
          #pragma unroll
          for (int j = 0; j < 4; ++j)
            gtile[wr * 64 + m * 16 + crow + j][wc2 * 32 + n * 16 + ccol] = acc[m][n][j];
      __syncthreads();

      int row = tid >> 1;
      int q0 = (tid & 1) * 8;
      int grow = row0 + row;
      int ch0 = role * 16 + q0;
      float4* cb = (float4*)(cbuf + (size_t)grow * HS + ch0);
      float4 cv0 = cb[0], cv1 = cb[1];
      float cold[8] = {cv0.x, cv0.y, cv0.z, cv0.w, cv1.x, cv1.y, cv1.z, cv1.w};
      float c2v[8], h2v[8];
      #pragma unroll
      for (int k = 0; k < 8; ++k) {
        int q = q0 + k;
        float ig = gtile[row][q]      + sbias[q];
        float fg = gtile[row][16 + q] + sbias[16 + q];
        float gg = gtile[row][32 + q] + sbias[32 + q];
        float og = gtile[row][48 + q] + sbias[48 + q];
        float c2 = sigm(fg) * cold[k] + sigm(ig) * tanhf(gg);
        c2v[k] = c2;
        h2v[k] = sigm(og) * tanhf(c2);
      }
      cb[0] = (float4){c2v[0], c2v[1], c2v[2], c2v[3]};
      cb[1] = (float4){c2v[4], c2v[5], c2v[6], c2v[7]};
      u16x8 hx;
      #pragma unroll
      for (int k = 0; k < 8; ++k) hx[k] = f2bf(h2v[k]);
      *(u16x8*)(Xnext + (size_t)grow * KX + 576 + ch0) = hx;
    }

    batch_barrier(cnt, gen);
  }

  // final head t=63; h2(63) is in X0 (t=63 odd -> Xnext = X0)
  head_fin_dev(data, W_r, b_r, Whead, bhead, X0, out, n0, T_ - 1, tid);
}

extern "C" void kernel_launch(void* const* d_in, const int* in_sizes, int n_in,
                              void* d_out, int out_size, void* d_ws, size_t ws_size,
                              hipStream_t stream) {
  const float* data = (const float*)d_in[0];
  const float* W_r  = (const float*)d_in[2];
  const float* b_r  = (const float*)d_in[3];
  const float* W_e  = (const float*)d_in[4];
  const float* b_e  = (const float*)d_in[5];
  const float* W_ih = (const float*)d_in[6];
  const float* W_hh = (const float*)d_in[7];
  const float* b_ih = (const float*)d_in[8];
  const float* b_hh = (const float*)d_in[9];
  const float* W_p  = (const float*)d_in[10];
  const float* b_p  = (const float*)d_in[11];
  const float* W_p2 = (const float*)d_in[12];
  const float* b_p2 = (const float*)d_in[13];
  const float* W_mu = (const float*)d_in[14];
  const float* b_mu = (const float*)d_in[15];
  const float* W_sd = (const float*)d_in[16];
  const float* b_sd = (const float*)d_in[17];
  const float* W_cr = (const float*)d_in[18];
  const float* b_cr = (const float*)d_in[19];
  float* out = (float*)d_out;

  char* ws = (char*)d_ws;
  float* cbuf  = (float*)(ws);                                // 4 MB
  unsigned short* Xbf0 = (unsigned short*)(ws + (4u  << 20)); // 6.5 MB
  unsigned short* Xbf1 = (unsigned short*)(ws + (11u << 20)); // 6.5 MB
  unsigned short* Wc   = (unsigned short*)(ws + (18u << 20)); // 1.7 MB
  float* bsum  = (float*)(ws + (20u << 20));                  // 4 KB
  float* Whead = (float*)(ws + (20u << 20) + 8192);           // 6.4 KB
  float* bhead = (float*)(ws + (20u << 20) + 16384);          // 20 B
  unsigned short* Web = (unsigned short*)(ws + (20u << 20) + 20480); // 16 KB
  int* bar = (int*)(ws + (21u << 20));                        // 8 KB

  hipMemsetAsync(cbuf, 0, (size_t)N_ * HS * sizeof(float), stream);
  hipMemsetAsync(Xbf0, 0, (size_t)N_ * KX * sizeof(unsigned short), stream);
  hipMemsetAsync(bar,  0, 32 * 64 * sizeof(int), stream);

  k_wcat<<<(GD * KX + GD + ES * HS + 255) / 256, 256, 0, stream>>>(
      W_ih, W_hh, b_ih, b_hh, W_e, Wc, bsum, Web);
  k_head<<<5, 320, 0, stream>>>(W_p, b_p, W_p2, b_p2, W_mu, b_mu, W_sd, b_sd, W_cr, b_cr,
                                Whead, bhead);

  k_persist<<<512, 256, 0, stream>>>(data, Web, b_e, Whead, bhead, W_r, b_r,
                                     Wc, bsum, cbuf, Xbf0, Xbf1, bar, out);
}

// Round 9
// 2378.100 us; speedup vs baseline: 3.2985x; 3.2985x over previous
//
#include <hip/hip_runtime.h>
#include <hip/hip_bf16.h>

#define B_  32
#define A_  128
#define T_  64
#define N_  4096        // B_*A_
#define HS  256
#define ES  32
#define RS  64
#define KX  832         // 64 (r) + 512 (e) + 256 (h)
#define GD  1024        // 4*HS
#define NKT 26          // KX/32

typedef __attribute__((ext_vector_type(8))) short bf8_t;            // 8 x bf16
typedef __attribute__((ext_vector_type(8))) unsigned short u16x8;
typedef __attribute__((ext_vector_type(4))) float f4_t;             // mfma acc
typedef __attribute__((ext_vector_type(2))) float f2_t;

__device__ __forceinline__ unsigned short f2bf(float x) {
  union { float f; unsigned u; } v; v.f = x;
  unsigned u = v.u;
  u += 0x7fffu + ((u >> 16) & 1u);     // round-to-nearest-even
  return (unsigned short)(u >> 16);
}
__device__ __forceinline__ float bf2f(unsigned short u) {
  union { unsigned u; float f; } v; v.u = ((unsigned)u) << 16; return v.f;
}
__device__ __forceinline__ float sigm(float x) { return 1.f / (1.f + __expf(-x)); }

__device__ __forceinline__ void gload16(const void* g, void* l) {
  __builtin_amdgcn_global_load_lds((const __attribute__((address_space(1))) void*)g,
                                   (__attribute__((address_space(3))) void*)l, 16, 0, 0);
}

// ---- Wc (permuted) + fused bias + bf16 W_e copy
__global__ void k_wcat(const float* __restrict__ W_ih, const float* __restrict__ W_hh,
                       const float* __restrict__ b_ih, const float* __restrict__ b_hh,
                       const float* __restrict__ W_e,
                       unsigned short* __restrict__ Wc, float* __restrict__ bsum,
                       unsigned short* __restrict__ Web) {
  int i = blockIdx.x * 256 + threadIdx.x;
  if (i < GD * KX) {
    int mp = i / KX, k = i - mp * KX;
    int nb = mp >> 6, rem = mp & 63, g = rem >> 4, q = rem & 15;
    int mo = g * 256 + nb * 16 + q;
    float v = (k < 576) ? W_ih[mo * 576 + k] : W_hh[mo * 256 + (k - 576)];
    Wc[i] = f2bf(v);
  } else if (i < GD * KX + GD) {
    int j = i - GD * KX;
    int nb = j >> 6, rem = j & 63, g = rem >> 4, q = rem & 15;
    int mo = g * 256 + nb * 16 + q;
    bsum[j] = b_ih[mo] + b_hh[mo];
  } else if (i < GD * KX + GD + ES * HS) {
    int j2 = i - GD * KX - GD;
    Web[j2] = f2bf(W_e[j2]);
  }
}

// ---- collapsed head: Whead[o][320] = (Wo @ W_p2) @ W_p   (5 blocks x 320 thr)
__global__ __launch_bounds__(320) void k_head(
    const float* __restrict__ W_p, const float* __restrict__ b_p,
    const float* __restrict__ W_p2, const float* __restrict__ b_p2,
    const float* __restrict__ W_mu, const float* __restrict__ b_mu,
    const float* __restrict__ W_sd, const float* __restrict__ b_sd,
    const float* __restrict__ W_cr, const float* __restrict__ b_cr,
    float* __restrict__ Whead, float* __restrict__ bhead) {
  int o = blockIdx.x, tid = threadIdx.x;
  __shared__ float to[64];
  const float* Wo = (o < 2) ? W_mu + o * 32 : (o < 4) ? W_sd + (o - 2) * 32 : W_cr;
  if (tid < 64) {
    float a = 0.f;
    #pragma unroll 8
    for (int c = 0; c < 32; ++c) a += Wo[c] * W_p2[c * 64 + tid];
    to[tid] = a;
  }
  __syncthreads();
  float a = 0.f;
  #pragma unroll 8
  for (int j = 0; j < 64; ++j) a += to[j] * W_p[j * 320 + tid];
  Whead[o * 320 + tid] = a;
  if (tid == 0) {
    float b0 = (o < 2) ? b_mu[o] : (o < 4) ? b_sd[o - 2] : b_cr[0];
    float acc = b0;
    for (int c = 0; c < 32; ++c) acc += Wo[c] * b_p2[c];
    for (int j = 0; j < 64; ++j) acc += to[j] * b_p[j];
    bhead[o] = acc;
  }
}

// ---- head for step ts, rows n0..n0+8. h2(ts) is the bf16 h-part of Xh.
__device__ __forceinline__ void head_fin_dev(
    const float* __restrict__ data, const float* __restrict__ W_r,
    const float* __restrict__ b_r, const float* __restrict__ Whead,
    const float* __restrict__ bhead, const unsigned short* __restrict__ Xh,
    float* __restrict__ out, int n0, int ts, int tid) {
  int r8 = tid >> 5, ln = tid & 31;
  int n = n0 + r8;
  float s0 = 0.f, s1 = 0.f, s2 = 0.f, s3 = 0.f, s4 = 0.f;
  u16x8 hv = *(const u16x8*)(Xh + (size_t)n * KX + 576 + ln * 8);
  float hf[8];
  #pragma unroll
  for (int k = 0; k < 8; ++k) hf[k] = bf2f(hv[k]);
  #pragma unroll
  for (int k = 0; k < 8; ++k) {
    int kk = 64 + ln * 8 + k;
    s0 += hf[k] * Whead[0 * 320 + kk];
    s1 += hf[k] * Whead[1 * 320 + kk];
    s2 += hf[k] * Whead[2 * 320 + kk];
    s3 += hf[k] * Whead[3 * 320 + kk];
    s4 += hf[k] * Whead[4 * 320 + kk];
  }
  float x0 = data[(n * T_ + ts) * 2 + 0];
  float x1 = data[(n * T_ + ts) * 2 + 1];
  #pragma unroll
  for (int l2 = 0; l2 < 2; ++l2) {
    int l = ln + 32 * l2;
    float rv = fmaxf(x0 * W_r[l * 2] + x1 * W_r[l * 2 + 1] + b_r[l], 0.f);
    s0 += rv * Whead[0 * 320 + l];
    s1 += rv * Whead[1 * 320 + l];
    s2 += rv * Whead[2 * 320 + l];
    s3 += rv * Whead[3 * 320 + l];
    s4 += rv * Whead[4 * 320 + l];
  }
  #pragma unroll
  for (int off = 16; off; off >>= 1) {
    s0 += __shfl_xor(s0, off);
    s1 += __shfl_xor(s1, off);
    s2 += __shfl_xor(s2, off);
    s3 += __shfl_xor(s3, off);
    s4 += __shfl_xor(s4, off);
  }
  if (ln == 0) {
    out[(n * T_ + ts) * 2 + 0] = s0 + bhead[0];
    out[(n * T_ + ts) * 2 + 1] = s1 + bhead[1];
    out[N_ * T_ * 2 + (n * T_ + ts) * 2 + 0] = __expf(s2 + bhead[2]);
    out[N_ * T_ * 2 + (n * T_ + ts) * 2 + 1] = __expf(s3 + bhead[3]);
    out[N_ * T_ * 4 + n * T_ + ts] = tanhf(s4 + bhead[4]);
  }
}

// ---- social: head(t-1) finalize + r(t) write + hW via MFMA + outer-product e
__global__ __launch_bounds__(256) void k_social(
    const float* __restrict__ data, const unsigned short* __restrict__ Web,
    const float* __restrict__ b_e, unsigned short* __restrict__ Xcur,
    const float* __restrict__ Whead, const float* __restrict__ bhead,
    const float* __restrict__ W_r, const float* __restrict__ b_r,
    float* __restrict__ out, int t) {
  int b  = blockIdx.x >> 4;
  int ig = blockIdx.x & 15;
  int n0 = b * A_ + ig * 8;
  __shared__ float sx[A_], sy[A_];
  __shared__ float shw2[64 * 64];     // [jp][c][sub]  16 KB
  __shared__ float smx[8][64][8];     // 16 KB
  __shared__ float smy[8][64][8];     // 16 KB
  int tid = threadIdx.x;
  if (tid < A_) {
    sx[tid] = data[((b * A_ + tid) * T_ + t) * 2 + 0];
    sy[tid] = data[((b * A_ + tid) * T_ + t) * 2 + 1];
  }
  if (t > 0)
    head_fin_dev(data, W_r, b_r, Whead, bhead, Xcur, out, n0, t - 1, tid);
  for (int u = tid; u < 512; u += 256) {
    int rr = u >> 6, l = u & 63;
    int n = n0 + rr;
    float x0 = data[(n * T_ + t) * 2 + 0];
    float x1 = data[(n * T_ + t) * 2 + 1];
    Xcur[(size_t)n * KX + l] =
        f2bf(fmaxf(x0 * W_r[l * 2] + x1 * W_r[l * 2 + 1] + b_r[l], 0.f));
  }
  // hW = h2 @ W_e^T via MFMA; wave wv handles rows wv*32..+32 of batch b
  {
    int wv = tid >> 6, lane = tid & 63;
    int lr = lane & 15, lh = lane >> 4;
    const unsigned short* a0p = Xcur + (size_t)(b * A_ + wv * 32 + lr) * KX + 576 + lh * 8;
    const unsigned short* a1p = a0p + 16 * KX;
    const unsigned short* b0p = Web + lr * HS + lh * 8;
    const unsigned short* b1p = Web + (16 + lr) * HS + lh * 8;
    f4_t hacc[2][2];
    hacc[0][0] = (f4_t){0.f,0.f,0.f,0.f}; hacc[0][1] = hacc[0][0];
    hacc[1][0] = hacc[0][0];              hacc[1][1] = hacc[0][0];
    #pragma unroll
    for (int kk = 0; kk < 8; ++kk) {
      bf8_t av0 = *(const bf8_t*)(a0p + kk * 32);
      bf8_t av1 = *(const bf8_t*)(a1p + kk * 32);
      bf8_t bv0 = *(const bf8_t*)(b0p + kk * 32);
      bf8_t bv1 = *(const bf8_t*)(b1p + kk * 32);
      hacc[0][0] = __builtin_amdgcn_mfma_f32_16x16x32_bf16(av0, bv0, hacc[0][0], 0, 0, 0);
      hacc[0][1] = __builtin_amdgcn_mfma_f32_16x16x32_bf16(av0, bv1, hacc[0][1], 0, 0, 0);
      hacc[1][0] = __builtin_amdgcn_mfma_f32_16x16x32_bf16(av1, bv0, hacc[1][0], 0, 0, 0);
      hacc[1][1] = __builtin_amdgcn_mfma_f32_16x16x32_bf16(av1, bv1, hacc[1][1], 0, 0, 0);
    }
    int ccol = lane & 15, crow4 = (lane >> 4) * 4;
    #pragma unroll
    for (int m = 0; m < 2; ++m)
      #pragma unroll
      for (int cb2 = 0; cb2 < 2; ++cb2)
        #pragma unroll
        for (int j = 0; j < 4; ++j) {
          int rr = wv * 32 + m * 16 + crow4 + j;
          int c  = cb2 * 16 + ccol;
          shw2[(rr >> 1) * 64 + c * 2 + (rr & 1)] = hacc[m][cb2][j];
        }
  }
  __syncthreads();

  // phase 1: indicators
  for (int u = tid; u < 512; u += 256) {
    int r = u >> 6, jp = u & 63;
    int irow = ig * 8 + r;
    float xi = sx[irow], yi = sy[irow];
    bool acti = xi >= 0.f;
    float m0[4], m1[4], nn0[4], nn1[4];
    #pragma unroll
    for (int s = 0; s < 2; ++s) {
      int j = jp * 2 + s;
      float xj = sx[j], yj = sy[j];
      bool v = acti && (xj >= 0.f) && (j != irow);
      float dx = xi - xj, dy = yi - yj;
      float* mm = s ? m1 : m0;
      float* nn = s ? nn1 : nn0;
      mm[0] = (v && dx >= 8.f   && dx <= 16.f) ? 1.f : 0.f;
      mm[1] = (v && dx >= 0.f   && dx <= 8.f ) ? 1.f : 0.f;
      mm[2] = (v && dx >= -8.f  && dx <= 0.f ) ? 1.f : 0.f;
      mm[3] = (v && dx >= -16.f && dx <= -8.f) ? 1.f : 0.f;
      nn[0] = (dy >= -16.f && dy <= -8.f) ? 1.f : 0.f;
      nn[1] = (dy >= -8.f  && dy <= 0.f ) ? 1.f : 0.f;
      nn[2] = (dy >= 0.f   && dy <= 8.f ) ? 1.f : 0.f;
      nn[3] = (dy >= 8.f   && dy <= 16.f) ? 1.f : 0.f;
    }
    float4* px = (float4*)&smx[r][jp][0];
    px[0] = (float4){m0[0], m1[0], m0[1], m1[1]};
    px[1] = (float4){m0[2], m1[2], m0[3], m1[3]};
    float4* py = (float4*)&smy[r][jp][0];
    py[0] = (float4){nn0[0], nn1[0], nn0[1], nn1[1]};
    py[1] = (float4){nn0[2], nn1[2], nn0[3], nn1[3]};
  }
  __syncthreads();

  // phase 2: register accumulate, f2 (paired j) math
  int half = tid >> 5;               // row within group
  int lane = tid & 31;               // channel
  f2_t acc[16];
  #pragma unroll
  for (int g = 0; g < 16; ++g) acc[g] = (f2_t){0.f, 0.f};
  #pragma unroll 2
  for (int jp = 0; jp < 64; ++jp) {
    f2_t hv = *(const f2_t*)&shw2[jp * 64 + lane * 2];
    float4 xa = ((const float4*)&smx[half][jp][0])[0];
    float4 xb = ((const float4*)&smx[half][jp][0])[1];
    float4 ya = ((const float4*)&smy[half][jp][0])[0];
    float4 yb = ((const float4*)&smy[half][jp][0])[1];
    f2_t mx[4] = {(f2_t){xa.x, xa.y}, (f2_t){xa.z, xa.w},
                  (f2_t){xb.x, xb.y}, (f2_t){xb.z, xb.w}};
    f2_t p[4]  = {(f2_t){ya.x, ya.y} * hv, (f2_t){ya.z, ya.w} * hv,
                  (f2_t){yb.x, yb.y} * hv, (f2_t){yb.z, yb.w} * hv};
    #pragma unroll
    for (int gy = 0; gy < 4; ++gy)
      #pragma unroll
      for (int gx = 0; gx < 4; ++gx)
        acc[gy * 4 + gx] += mx[gx] * p[gy];
  }

  // epilogue: e -> Xcur at torch-reshape-permuted location
  int irow = ig * 8 + half;
  float be = b_e[lane];
  int hi = irow >> 4;
  int klo = (irow & 15) * ES + lane;
  #pragma unroll
  for (int g = 0; g < 16; ++g) {
    float e = fmaxf(acc[g][0] + acc[g][1] + be, 0.f);
    int a_out = g * 8 + hi;
    Xcur[(b * A_ + a_out) * KX + 64 + klo] = f2bf(e);
  }
}

// ---- gates GEMM (permuted cols) + register-direct LSTM pointwise.
// BM=128 (one batch), BN=128, BK=32, 512 threads (8 waves: wr=w>>1 rows,
// wc=w&1 64-col gate group). Each wave's 4 n-tiles = the 4 gates (i,f,g,o)
// of channel q=lane&15 -> LSTM pointwise entirely in registers (no gtile).
// grid 256: tm = bid&31 (batch), tc = bid>>5 -> A-panel blocks share an XCD.
__global__ __launch_bounds__(512) void k_gemm_lstm(
    const unsigned short* __restrict__ Xcur, const unsigned short* __restrict__ Wc,
    const float* __restrict__ bsum,
    float* __restrict__ cbuf, unsigned short* __restrict__ Xnext) {
  __shared__ unsigned short sA0[128 * 32];   // 8 KB
  __shared__ unsigned short sB0[128 * 32];   // 8 KB
  __shared__ unsigned short sA1[128 * 32];
  __shared__ unsigned short sB1[128 * 32];

  int bid = blockIdx.x;
  int tm = bid & 31, tc = bid >> 5;
  int row0 = tm * 128, col0 = tc * 128;
  int tid = threadIdx.x;
  int lane = tid & 63;
  int w = tid >> 6;
  int wr = w >> 1, wc = w & 1;              // 8 waves: 32 rows x 64 cols each
  int lr = lane & 15, lh = lane >> 4;

  // staging: thread -> (row tid>>2, chunk tid&3), global chunk pre-swizzled
  int srow = tid >> 2, schunk = tid & 3;
  int gch = (schunk ^ ((srow >> 1) & 3)) * 8;
  const unsigned short* gA = Xcur + (size_t)(row0 + srow) * KX + gch;
  const unsigned short* gB = Wc  + (size_t)(col0 + srow) * KX + gch;

  int swz = (lh ^ ((lr >> 1) & 3)) * 8;
  int aoff[2], boff[4];
  #pragma unroll
  for (int m = 0; m < 2; ++m) aoff[m] = (wr * 32 + m * 16 + lr) * 32 + swz;
  #pragma unroll
  for (int n = 0; n < 4; ++n) boff[n] = (wc * 64 + n * 16 + lr) * 32 + swz;

  // per-lane gate biases
  int q = lane & 15;
  float bias_g[4];
  #pragma unroll
  for (int n = 0; n < 4; ++n) bias_g[n] = bsum[col0 + wc * 64 + n * 16 + q];

  f4_t acc[2][4];
  #pragma unroll
  for (int m = 0; m < 2; ++m)
    #pragma unroll
    for (int n = 0; n < 4; ++n) acc[m][n] = (f4_t){0.f, 0.f, 0.f, 0.f};

#define STAGE(pA, pB, kt) do { \
    gload16(gA + (kt) * 32, (pA) + tid * 8); \
    gload16(gB + (kt) * 32, (pB) + tid * 8); \
  } while (0)

#define COMPUTE(pA, pB) do { \
    bf8_t a_[2], b_[4]; \
    _Pragma("unroll") for (int m = 0; m < 2; ++m) a_[m] = *(const bf8_t*)((pA) + aoff[m]); \
    _Pragma("unroll") for (int n = 0; n < 4; ++n) b_[n] = *(const bf8_t*)((pB) + boff[n]); \
    _Pragma("unroll") for (int m = 0; m < 2; ++m) \
      _Pragma("unroll") for (int n = 0; n < 4; ++n) \
        acc[m][n] = __builtin_amdgcn_mfma_f32_16x16x32_bf16(a_[m], b_[n], acc[m][n], 0, 0, 0); \
  } while (0)

  STAGE(sA0, sB0, 0);
  __syncthreads();
  #pragma unroll 1
  for (int kt = 0; kt < NKT; kt += 2) {
    STAGE(sA1, sB1, kt + 1);          // kt+1 <= 25 (NKT even)
    COMPUTE(sA0, sB0);
    __syncthreads();
    if (kt + 2 < NKT) STAGE(sA0, sB0, kt + 2);
    COMPUTE(sA1, sB1);
    __syncthreads();
  }
#undef STAGE
#undef COMPUTE

  // register-direct LSTM pointwise: lane owns channel ch, rows jrow4+j per m
  int ch = (tc * 2 + wc) * 16 + q;
  int jrow4 = (lane >> 4) * 4;
  #pragma unroll
  for (int m = 0; m < 2; ++m) {
    #pragma unroll
    for (int j = 0; j < 4; ++j) {
      int row = row0 + wr * 32 + m * 16 + jrow4 + j;
      float ig = acc[m][0][j] + bias_g[0];
      float fg = acc[m][1][j] + bias_g[1];
      float gg = acc[m][2][j] + bias_g[2];
      float og = acc[m][3][j] + bias_g[3];
      float cold = cbuf[(size_t)row * HS + ch];
      float c2 = sigm(fg) * cold + sigm(ig) * tanhf(gg);
      float h2 = sigm(og) * tanhf(c2);
      cbuf[(size_t)row * HS + ch] = c2;
      Xnext[(size_t)row * KX + 576 + ch] = f2bf(h2);
    }
  }
}

// ---- final head for t=63 (512 blocks x 8 rows); Xh = X holding h2(63)
__global__ __launch_bounds__(256) void k_fin(
    const float* __restrict__ data, const float* __restrict__ W_r,
    const float* __restrict__ b_r, const float* __restrict__ Whead,
    const float* __restrict__ bhead, const unsigned short* __restrict__ Xh,
    float* __restrict__ out) {
  head_fin_dev(data, W_r, b_r, Whead, bhead, Xh, out,
               blockIdx.x * 8, T_ - 1, threadIdx.x);
}

extern "C" void kernel_launch(void* const* d_in, const int* in_sizes, int n_in,
                              void* d_out, int out_size, void* d_ws, size_t ws_size,
                              hipStream_t stream) {
  const float* data = (const float*)d_in[0];
  const float* W_r  = (const float*)d_in[2];
  const float* b_r  = (const float*)d_in[3];
  const float* W_e  = (const float*)d_in[4];
  const float* b_e  = (const float*)d_in[5];
  const float* W_ih = (const float*)d_in[6];
  const float* W_hh = (const float*)d_in[7];
  const float* b_ih = (const float*)d_in[8];
  const float* b_hh = (const float*)d_in[9];
  const float* W_p  = (const float*)d_in[10];
  const float* b_p  = (const float*)d_in[11];
  const float* W_p2 = (const float*)d_in[12];
  const float* b_p2 = (const float*)d_in[13];
  const float* W_mu = (const float*)d_in[14];
  const float* b_mu = (const float*)d_in[15];
  const float* W_sd = (const float*)d_in[16];
  const float* b_sd = (const float*)d_in[17];
  const float* W_cr = (const float*)d_in[18];
  const float* b_cr = (const float*)d_in[19];
  float* out = (float*)d_out;

  char* ws = (char*)d_ws;
  float* cbuf  = (float*)(ws);                                // 4 MB
  unsigned short* Xbf0 = (unsigned short*)(ws + (4u  << 20)); // 6.5 MB
  unsigned short* Xbf1 = (unsigned short*)(ws + (11u << 20)); // 6.5 MB
  unsigned short* Wc   = (unsigned short*)(ws + (18u << 20)); // 1.7 MB
  float* bsum  = (float*)(ws + (20u << 20));                  // 4 KB
  float* Whead = (float*)(ws + (20u << 20) + 8192);           // 6.4 KB
  float* bhead = (float*)(ws + (20u << 20) + 16384);          // 20 B
  unsigned short* Web = (unsigned short*)(ws + (20u << 20) + 20480); // 16 KB

  hipMemsetAsync(cbuf, 0, (size_t)N_ * HS * sizeof(float), stream);
  hipMemsetAsync(Xbf0, 0, (size_t)N_ * KX * sizeof(unsigned short), stream);

  k_wcat<<<(GD * KX + GD + ES * HS + 255) / 256, 256, 0, stream>>>(
      W_ih, W_hh, b_ih, b_hh, W_e, Wc, bsum, Web);
  k_head<<<5, 320, 0, stream>>>(W_p, b_p, W_p2, b_p2, W_mu, b_mu, W_sd, b_sd, W_cr, b_cr,
                                Whead, bhead);

  for (int t = 0; t < T_; ++t) {
    unsigned short* Xcur  = (t & 1) ? Xbf1 : Xbf0;
    unsigned short* Xnext = (t & 1) ? Xbf0 : Xbf1;
    k_social<<<512, 256, 0, stream>>>(data, Web, b_e, Xcur, Whead, bhead,
                                      W_r, b_r, out, t);
    k_gemm_lstm<<<256, 512, 0, stream>>>(Xcur, Wc, bsum, cbuf, Xnext);
  }
  // h2(63) lives in Xnext of t=63 -> Xbf0 (t=63 odd)
  k_fin<<<512, 256, 0, stream>>>(data, W_r, b_r, Whead, bhead, Xbf0, out);
}

// Round 10
// 2185.377 us; speedup vs baseline: 3.5894x; 1.0882x over previous
//
#include <hip/hip_runtime.h>
#include <hip/hip_bf16.h>

#define B_  32
#define A_  128
#define T_  64
#define N_  4096        // B_*A_
#define HS  256
#define ES  32
#define RS  64
#define KX  832         // 64 (r) + 512 (e) + 256 (h)
#define GD  1024        // 4*HS

typedef __attribute__((ext_vector_type(8))) short bf8_t;            // 8 x bf16
typedef __attribute__((ext_vector_type(8))) unsigned short u16x8;
typedef __attribute__((ext_vector_type(4))) float f4_t;             // mfma acc
typedef __attribute__((ext_vector_type(2))) float f2_t;

__device__ __forceinline__ unsigned short f2bf(float x) {
  union { float f; unsigned u; } v; v.f = x;
  unsigned u = v.u;
  u += 0x7fffu + ((u >> 16) & 1u);     // round-to-nearest-even
  return (unsigned short)(u >> 16);
}
__device__ __forceinline__ float bf2f(unsigned short u) {
  union { unsigned u; float f; } v; v.u = ((unsigned)u) << 16; return v.f;
}
__device__ __forceinline__ float sigm(float x) { return 1.f / (1.f + __expf(-x)); }

__device__ __forceinline__ void gload16(const void* g, void* l) {
  __builtin_amdgcn_global_load_lds((const __attribute__((address_space(1))) void*)g,
                                   (__attribute__((address_space(3))) void*)l, 16, 0, 0);
}

// ---- Wc (permuted) + fused bias + bf16 W_e copy
__global__ void k_wcat(const float* __restrict__ W_ih, const float* __restrict__ W_hh,
                       const float* __restrict__ b_ih, const float* __restrict__ b_hh,
                       const float* __restrict__ W_e,
                       unsigned short* __restrict__ Wc, float* __restrict__ bsum,
                       unsigned short* __restrict__ Web) {
  int i = blockIdx.x * 256 + threadIdx.x;
  if (i < GD * KX) {
    int mp = i / KX, k = i - mp * KX;
    int nb = mp >> 6, rem = mp & 63, g = rem >> 4, q = rem & 15;
    int mo = g * 256 + nb * 16 + q;
    float v = (k < 576) ? W_ih[mo * 576 + k] : W_hh[mo * 256 + (k - 576)];
    Wc[i] = f2bf(v);
  } else if (i < GD * KX + GD) {
    int j = i - GD * KX;
    int nb = j >> 6, rem = j & 63, g = rem >> 4, q = rem & 15;
    int mo = g * 256 + nb * 16 + q;
    bsum[j] = b_ih[mo] + b_hh[mo];
  } else if (i < GD * KX + GD + ES * HS) {
    int j2 = i - GD * KX - GD;
    Web[j2] = f2bf(W_e[j2]);
  }
}

// ---- collapsed head: Whead[o][320] = (Wo @ W_p2) @ W_p   (5 blocks x 320 thr)
__global__ __launch_bounds__(320) void k_head(
    const float* __restrict__ W_p, const float* __restrict__ b_p,
    const float* __restrict__ W_p2, const float* __restrict__ b_p2,
    const float* __restrict__ W_mu, const float* __restrict__ b_mu,
    const float* __restrict__ W_sd, const float* __restrict__ b_sd,
    const float* __restrict__ W_cr, const float* __restrict__ b_cr,
    float* __restrict__ Whead, float* __restrict__ bhead) {
  int o = blockIdx.x, tid = threadIdx.x;
  __shared__ float to[64];
  const float* Wo = (o < 2) ? W_mu + o * 32 : (o < 4) ? W_sd + (o - 2) * 32 : W_cr;
  if (tid < 64) {
    float a = 0.f;
    #pragma unroll 8
    for (int c = 0; c < 32; ++c) a += Wo[c] * W_p2[c * 64 + tid];
    to[tid] = a;
  }
  __syncthreads();
  float a = 0.f;
  #pragma unroll 8
  for (int j = 0; j < 64; ++j) a += to[j] * W_p[j * 320 + tid];
  Whead[o * 320 + tid] = a;
  if (tid == 0) {
    float b0 = (o < 2) ? b_mu[o] : (o < 4) ? b_sd[o - 2] : b_cr[0];
    float acc = b0;
    for (int c = 0; c < 32; ++c) acc += Wo[c] * b_p2[c];
    for (int j = 0; j < 64; ++j) acc += to[j] * b_p[j];
    bhead[o] = acc;
  }
}

// ---- head for step ts, rows n0..n0+(threads/32). h2(ts) = bf16 h-part of Xh.
__device__ __forceinline__ void head_fin_dev(
    const float* __restrict__ data, const float* __restrict__ W_r,
    const float* __restrict__ b_r, const float* __restrict__ Whead,
    const float* __restrict__ bhead, const unsigned short* __restrict__ Xh,
    float* __restrict__ out, int n0, int ts, int tid) {
  int r8 = tid >> 5, ln = tid & 31;
  int n = n0 + r8;
  float s0 = 0.f, s1 = 0.f, s2 = 0.f, s3 = 0.f, s4 = 0.f;
  u16x8 hv = *(const u16x8*)(Xh + (size_t)n * KX + 576 + ln * 8);
  float hf[8];
  #pragma unroll
  for (int k = 0; k < 8; ++k) hf[k] = bf2f(hv[k]);
  #pragma unroll
  for (int k = 0; k < 8; ++k) {
    int kk = 64 + ln * 8 + k;
    s0 += hf[k] * Whead[0 * 320 + kk];
    s1 += hf[k] * Whead[1 * 320 + kk];
    s2 += hf[k] * Whead[2 * 320 + kk];
    s3 += hf[k] * Whead[3 * 320 + kk];
    s4 += hf[k] * Whead[4 * 320 + kk];
  }
  float x0 = data[(n * T_ + ts) * 2 + 0];
  float x1 = data[(n * T_ + ts) * 2 + 1];
  #pragma unroll
  for (int l2 = 0; l2 < 2; ++l2) {
    int l = ln + 32 * l2;
    float rv = fmaxf(x0 * W_r[l * 2] + x1 * W_r[l * 2 + 1] + b_r[l], 0.f);
    s0 += rv * Whead[0 * 320 + l];
    s1 += rv * Whead[1 * 320 + l];
    s2 += rv * Whead[2 * 320 + l];
    s3 += rv * Whead[3 * 320 + l];
    s4 += rv * Whead[4 * 320 + l];
  }
  #pragma unroll
  for (int off = 16; off; off >>= 1) {
    s0 += __shfl_xor(s0, off);
    s1 += __shfl_xor(s1, off);
    s2 += __shfl_xor(s2, off);
    s3 += __shfl_xor(s3, off);
    s4 += __shfl_xor(s4, off);
  }
  if (ln == 0) {
    out[(n * T_ + ts) * 2 + 0] = s0 + bhead[0];
    out[(n * T_ + ts) * 2 + 1] = s1 + bhead[1];
    out[N_ * T_ * 2 + (n * T_ + ts) * 2 + 0] = __expf(s2 + bhead[2]);
    out[N_ * T_ * 2 + (n * T_ + ts) * 2 + 1] = __expf(s3 + bhead[3]);
    out[N_ * T_ * 4 + n * T_ + ts] = tanhf(s4 + bhead[4]);
  }
}

// ---- social (256 blocks x 512 thr; block = (b, ig8) owning 16 rows):
// head(t-1) finalize + r(t) write + hW via MFMA + outer-product e.
// At t=0: skip hW MFMA (h=0 -> hW=0), zero shw2 + own rows' X h-part.
__global__ __launch_bounds__(512) void k_social(
    const float* __restrict__ data, const unsigned short* __restrict__ Web,
    const float* __restrict__ b_e, unsigned short* __restrict__ Xcur,
    const float* __restrict__ Whead, const float* __restrict__ bhead,
    const float* __restrict__ W_r, const float* __restrict__ b_r,
    float* __restrict__ out, int t) {
  int b   = blockIdx.x >> 3;
  int ig8 = blockIdx.x & 7;
  int n0  = b * A_ + ig8 * 16;
  __shared__ float sx[A_], sy[A_];
  __shared__ float shw2[64 * 64];       // [jp][c][sub]  16 KB
  __shared__ float smx[16][64][8];      // 32 KB
  __shared__ float smy[16][64][8];      // 32 KB
  int tid = threadIdx.x;
  if (tid < A_) {
    sx[tid] = data[((b * A_ + tid) * T_ + t) * 2 + 0];
    sy[tid] = data[((b * A_ + tid) * T_ + t) * 2 + 1];
  }
  if (t > 0)
    head_fin_dev(data, W_r, b_r, Whead, bhead, Xcur, out, n0, t - 1, tid);
  // r(t) -> Xcur rows n0..+16
  for (int u = tid; u < 1024; u += 512) {
    int rr = u >> 6, l = u & 63;
    int n = n0 + rr;
    float x0 = data[(n * T_ + t) * 2 + 0];
    float x1 = data[(n * T_ + t) * 2 + 1];
    Xcur[(size_t)n * KX + l] =
        f2bf(fmaxf(x0 * W_r[l * 2] + x1 * W_r[l * 2 + 1] + b_r[l], 0.f));
  }
  if (t == 0) {
    for (int i = tid; i < 64 * 64; i += 512) shw2[i] = 0.f;
    // zero the h-part of our own 16 rows (replaces the Xbf0 memset)
    u16x8 z = (u16x8){0, 0, 0, 0, 0, 0, 0, 0};
    int row = tid >> 5, c8 = tid & 31;
    *(u16x8*)(Xcur + (size_t)(n0 + row) * KX + 576 + c8 * 8) = z;
  } else {
    // hW = h2 @ W_e^T via MFMA; wave w covers rows w*16..+16 of batch b
    int w = tid >> 6, lane = tid & 63;
    int lr = lane & 15, lh = lane >> 4;
    const unsigned short* a0p = Xcur + (size_t)(b * A_ + w * 16 + lr) * KX + 576 + lh * 8;
    const unsigned short* b0p = Web + lr * HS + lh * 8;
    const unsigned short* b1p = Web + (16 + lr) * HS + lh * 8;
    f4_t hacc[2];
    hacc[0] = (f4_t){0.f, 0.f, 0.f, 0.f}; hacc[1] = hacc[0];
    #pragma unroll
    for (int kk = 0; kk < 8; ++kk) {
      bf8_t av  = *(const bf8_t*)(a0p + kk * 32);
      bf8_t bv0 = *(const bf8_t*)(b0p + kk * 32);
      bf8_t bv1 = *(const bf8_t*)(b1p + kk * 32);
      hacc[0] = __builtin_amdgcn_mfma_f32_16x16x32_bf16(av, bv0, hacc[0], 0, 0, 0);
      hacc[1] = __builtin_amdgcn_mfma_f32_16x16x32_bf16(av, bv1, hacc[1], 0, 0, 0);
    }
    int ccol = lane & 15, crow4 = (lane >> 4) * 4;
    #pragma unroll
    for (int cb2 = 0; cb2 < 2; ++cb2)
      #pragma unroll
      for (int j = 0; j < 4; ++j) {
        int rr = w * 16 + crow4 + j;
        int c  = cb2 * 16 + ccol;
        shw2[(rr >> 1) * 64 + c * 2 + (rr & 1)] = hacc[cb2][j];
      }
  }
  __syncthreads();

  // phase 1: indicators (1024 units = 16 rows x 64 j-pairs)
  for (int u = tid; u < 1024; u += 512) {
    int r = u >> 6, jp = u & 63;
    int irow = ig8 * 16 + r;
    float xi = sx[irow], yi = sy[irow];
    bool acti = xi >= 0.f;
    float m0[4], m1[4], nn0[4], nn1[4];
    #pragma unroll
    for (int s = 0; s < 2; ++s) {
      int j = jp * 2 + s;
      float xj = sx[j], yj = sy[j];
      bool v = acti && (xj >= 0.f) && (j != irow);
      float dx = xi - xj, dy = yi - yj;
      float* mm = s ? m1 : m0;
      float* nn = s ? nn1 : nn0;
      mm[0] = (v && dx >= 8.f   && dx <= 16.f) ? 1.f : 0.f;
      mm[1] = (v && dx >= 0.f   && dx <= 8.f ) ? 1.f : 0.f;
      mm[2] = (v && dx >= -8.f  && dx <= 0.f ) ? 1.f : 0.f;
      mm[3] = (v && dx >= -16.f && dx <= -8.f) ? 1.f : 0.f;
      nn[0] = (dy >= -16.f && dy <= -8.f) ? 1.f : 0.f;
      nn[1] = (dy >= -8.f  && dy <= 0.f ) ? 1.f : 0.f;
      nn[2] = (dy >= 0.f   && dy <= 8.f ) ? 1.f : 0.f;
      nn[3] = (dy >= 8.f   && dy <= 16.f) ? 1.f : 0.f;
    }
    float4* px = (float4*)&smx[r][jp][0];
    px[0] = (float4){m0[0], m1[0], m0[1], m1[1]};
    px[1] = (float4){m0[2], m1[2], m0[3], m1[3]};
    float4* py = (float4*)&smy[r][jp][0];
    py[0] = (float4){nn0[0], nn1[0], nn0[1], nn1[1]};
    py[1] = (float4){nn0[2], nn1[2], nn0[3], nn1[3]};
  }
  __syncthreads();

  // phase 2: register accumulate, f2 (paired j) math
  int half = tid >> 5;               // row 0..15
  int lane = tid & 31;               // channel
  f2_t acc[16];
  #pragma unroll
  for (int g = 0; g < 16; ++g) acc[g] = (f2_t){0.f, 0.f};
  #pragma unroll 2
  for (int jp = 0; jp < 64; ++jp) {
    f2_t hv = *(const f2_t*)&shw2[jp * 64 + lane * 2];
    float4 xa = ((const float4*)&smx[half][jp][0])[0];
    float4 xb = ((const float4*)&smx[half][jp][0])[1];
    float4 ya = ((const float4*)&smy[half][jp][0])[0];
    float4 yb = ((const float4*)&smy[half][jp][0])[1];
    f2_t mx[4] = {(f2_t){xa.x, xa.y}, (f2_t){xa.z, xa.w},
                  (f2_t){xb.x, xb.y}, (f2_t){xb.z, xb.w}};
    f2_t p[4]  = {(f2_t){ya.x, ya.y} * hv, (f2_t){ya.z, ya.w} * hv,
                  (f2_t){yb.x, yb.y} * hv, (f2_t){yb.z, yb.w} * hv};
    #pragma unroll
    for (int gy = 0; gy < 4; ++gy)
      #pragma unroll
      for (int gx = 0; gx < 4; ++gx)
        acc[gy * 4 + gx] += mx[gx] * p[gy];
  }

  // epilogue: e -> Xcur at torch-reshape-permuted location
  int irow = ig8 * 16 + half;
  float be = b_e[lane];
  int hi = irow >> 4;                // == ig8
  int klo = (irow & 15) * ES + lane;
  #pragma unroll
  for (int g = 0; g < 16; ++g) {
    float e = fmaxf(acc[g][0] + acc[g][1] + be, 0.f);
    int a_out = g * 8 + hi;
    Xcur[(size_t)(b * A_ + a_out) * KX + 64 + klo] = f2bf(e);
  }
}

// ---- gates GEMM (permuted cols) + register-direct LSTM pointwise.
// BM=128, BN=128, BK=64 (13 double-buffered stages), 512 threads.
__global__ __launch_bounds__(512) void k_gemm_lstm(
    const unsigned short* __restrict__ Xcur, const unsigned short* __restrict__ Wc,
    const float* __restrict__ bsum,
    float* __restrict__ cbuf, unsigned short* __restrict__ Xnext, int t) {
  __shared__ unsigned short sA0[128 * 64];   // 16 KB each
  __shared__ unsigned short sB0[128 * 64];
  __shared__ unsigned short sA1[128 * 64];
  __shared__ unsigned short sB1[128 * 64];

  int bid = blockIdx.x;
  int tm = bid & 31, tc = bid >> 5;
  int row0 = tm * 128, col0 = tc * 128;
  int tid = threadIdx.x;
  int lane = tid & 63;
  int w = tid >> 6;
  int wr = w >> 1, wc = w & 1;              // 8 waves: 32 rows x 64 cols each
  int lr = lane & 15, lh = lane >> 4;

  // staging: thread -> (row tid>>3, chunk tid&7); global chunk pre-swizzled
  int srow = tid >> 3, schunk = tid & 7;
  int gch = (schunk ^ ((srow >> 1) & 7)) * 8;
  const unsigned short* gA = Xcur + (size_t)(row0 + srow) * KX + gch;
  const unsigned short* gB = Wc  + (size_t)(col0 + srow) * KX + gch;
  // row+64 has identical swizzle (64>>1 = 32 == 0 mod 8)

  // fragment read offsets (shorts), swizzled chunk, per k-subtile kk
  int aoff[2][2], boff[4][2];
  #pragma unroll
  for (int m = 0; m < 2; ++m)
    #pragma unroll
    for (int kk = 0; kk < 2; ++kk)
      aoff[m][kk] = (wr * 32 + m * 16 + lr) * 64 + ((kk * 4 + lh) ^ ((lr >> 1) & 7)) * 8;
  #pragma unroll
  for (int n = 0; n < 4; ++n)
    #pragma unroll
    for (int kk = 0; kk < 2; ++kk)
      boff[n][kk] = (wc * 64 + n * 16 + lr) * 64 + ((kk * 4 + lh) ^ ((lr >> 1) & 7)) * 8;

  int q = lane & 15;
  float bias_g[4];
  #pragma unroll
  for (int n = 0; n < 4; ++n) bias_g[n] = bsum[col0 + wc * 64 + n * 16 + q];

  f4_t acc[2][4];
  #pragma unroll
  for (int m = 0; m < 2; ++m)
    #pragma unroll
    for (int n = 0; n < 4; ++n) acc[m][n] = (f4_t){0.f, 0.f, 0.f, 0.f};

#define STAGE(pA, pB, kt) do { \
    gload16(gA + (size_t)(kt) * 64, (pA) + tid * 8); \
    gload16(gA + (size_t)64 * KX + (kt) * 64, (pA) + 4096 + tid * 8); \
    gload16(gB + (size_t)(kt) * 64, (pB) + tid * 8); \
    gload16(gB + (size_t)64 * KX + (kt) * 64, (pB) + 4096 + tid * 8); \
  } while (0)

#define COMPUTE(pA, pB) do { \
    _Pragma("unroll") for (int kk = 0; kk < 2; ++kk) { \
      bf8_t a_[2], b_[4]; \
      _Pragma("unroll") for (int m = 0; m < 2; ++m) a_[m] = *(const bf8_t*)((pA) + aoff[m][kk]); \
      _Pragma("unroll") for (int n = 0; n < 4; ++n) b_[n] = *(const bf8_t*)((pB) + boff[n][kk]); \
      _Pragma("unroll") for (int m = 0; m < 2; ++m) \
        _Pragma("unroll") for (int n = 0; n < 4; ++n) \
          acc[m][n] = __builtin_amdgcn_mfma_f32_16x16x32_bf16(a_[m], b_[n], acc[m][n], 0, 0, 0); \
    } \
  } while (0)

  STAGE(sA0, sB0, 0);
  __syncthreads();
  #pragma unroll 1
  for (int kt = 0; kt < 12; kt += 2) {
    STAGE(sA1, sB1, kt + 1);
    COMPUTE(sA0, sB0);
    __syncthreads();
    STAGE(sA0, sB0, kt + 2);
    COMPUTE(sA1, sB1);
    __syncthreads();
  }
  COMPUTE(sA0, sB0);                 // kt = 12 (13 x 64 = 832)
#undef STAGE
#undef COMPUTE

  // register-direct LSTM pointwise
  int ch = (tc * 2 + wc) * 16 + q;
  int jrow4 = (lane >> 4) * 4;
  #pragma unroll
  for (int m = 0; m < 2; ++m) {
    #pragma unroll
    for (int j = 0; j < 4; ++j) {
      int row = row0 + wr * 32 + m * 16 + jrow4 + j;
      float ig = acc[m][0][j] + bias_g[0];
      float fg = acc[m][1][j] + bias_g[1];
      float gg = acc[m][2][j] + bias_g[2];
      float og = acc[m][3][j] + bias_g[3];
      float cold = (t == 0) ? 0.f : cbuf[(size_t)row * HS + ch];
      float c2 = sigm(fg) * cold + sigm(ig) * tanhf(gg);
      float h2 = sigm(og) * tanhf(c2);
      cbuf[(size_t)row * HS + ch] = c2;
      Xnext[(size_t)row * KX + 576 + ch] = f2bf(h2);
    }
  }
}

// ---- final head for t=63 (512 blocks x 8 rows); Xh = X holding h2(63)
__global__ __launch_bounds__(256) void k_fin(
    const float* __restrict__ data, const float* __restrict__ W_r,
    const float* __restrict__ b_r, const float* __restrict__ Whead,
    const float* __restrict__ bhead, const unsigned short* __restrict__ Xh,
    float* __restrict__ out) {
  head_fin_dev(data, W_r, b_r, Whead, bhead, Xh, out,
               blockIdx.x * 8, T_ - 1, threadIdx.x);
}

extern "C" void kernel_launch(void* const* d_in, const int* in_sizes, int n_in,
                              void* d_out, int out_size, void* d_ws, size_t ws_size,
                              hipStream_t stream) {
  const float* data = (const float*)d_in[0];
  const float* W_r  = (const float*)d_in[2];
  const float* b_r  = (const float*)d_in[3];
  const float* W_e  = (const float*)d_in[4];
  const float* b_e  = (const float*)d_in[5];
  const float* W_ih = (const float*)d_in[6];
  const float* W_hh = (const float*)d_in[7];
  const float* b_ih = (const float*)d_in[8];
  const float* b_hh = (const float*)d_in[9];
  const float* W_p  = (const float*)d_in[10];
  const float* b_p  = (const float*)d_in[11];
  const float* W_p2 = (const float*)d_in[12];
  const float* b_p2 = (const float*)d_in[13];
  const float* W_mu = (const float*)d_in[14];
  const float* b_mu = (const float*)d_in[15];
  const float* W_sd = (const float*)d_in[16];
  const float* b_sd = (const float*)d_in[17];
  const float* W_cr = (const float*)d_in[18];
  const float* b_cr = (const float*)d_in[19];
  float* out = (float*)d_out;

  char* ws = (char*)d_ws;
  float* cbuf  = (float*)(ws);                                // 4 MB
  unsigned short* Xbf0 = (unsigned short*)(ws + (4u  << 20)); // 6.5 MB
  unsigned short* Xbf1 = (unsigned short*)(ws + (11u << 20)); // 6.5 MB
  unsigned short* Wc   = (unsigned short*)(ws + (18u << 20)); // 1.7 MB
  float* bsum  = (float*)(ws + (20u << 20));                  // 4 KB
  float* Whead = (float*)(ws + (20u << 20) + 8192);           // 6.4 KB
  float* bhead = (float*)(ws + (20u << 20) + 16384);          // 20 B
  unsigned short* Web = (unsigned short*)(ws + (20u << 20) + 20480); // 16 KB

  k_wcat<<<(GD * KX + GD + ES * HS + 255) / 256, 256, 0, stream>>>(
      W_ih, W_hh, b_ih, b_hh, W_e, Wc, bsum, Web);
  k_head<<<5, 320, 0, stream>>>(W_p, b_p, W_p2, b_p2, W_mu, b_mu, W_sd, b_sd, W_cr, b_cr,
                                Whead, bhead);

  for (int t = 0; t < T_; ++t) {
    unsigned short* Xcur  = (t & 1) ? Xbf1 : Xbf0;
    unsigned short* Xnext = (t & 1) ? Xbf0 : Xbf1;
    k_social<<<256, 512, 0, stream>>>(data, Web, b_e, Xcur, Whead, bhead,
                                      W_r, b_r, out, t);
    k_gemm_lstm<<<256, 512, 0, stream>>>(Xcur, Wc, bsum, cbuf, Xnext, t);
  }
  // h2(63) lives in Xnext of t=63 -> Xbf0 (t=63 odd)
  k_fin<<<512, 256, 0, stream>>>(data, W_r, b_r, Whead, bhead, Xbf0, out);
}

// Round 11
// 2123.710 us; speedup vs baseline: 3.6937x; 1.0290x over previous
//
#include <hip/hip_runtime.h>
#include <hip/hip_bf16.h>

#define B_  32
#define A_  128
#define T_  64
#define N_  4096        // B_*A_
#define HS  256
#define ES  32
#define RS  64
#define KX  832         // 64 (r) + 512 (e) + 256 (h)
#define GD  1024        // 4*HS
#define NKT 26          // KX/32

typedef __attribute__((ext_vector_type(8))) short bf8_t;            // 8 x bf16
typedef __attribute__((ext_vector_type(8))) unsigned short u16x8;
typedef __attribute__((ext_vector_type(4))) float f4_t;             // mfma acc
typedef __attribute__((ext_vector_type(2))) float f2_t;

__device__ __forceinline__ unsigned short f2bf(float x) {
  union { float f; unsigned u; } v; v.f = x;
  unsigned u = v.u;
  u += 0x7fffu + ((u >> 16) & 1u);     // round-to-nearest-even
  return (unsigned short)(u >> 16);
}
__device__ __forceinline__ float bf2f(unsigned short u) {
  union { unsigned u; float f; } v; v.u = ((unsigned)u) << 16; return v.f;
}
__device__ __forceinline__ float sigm(float x) { return 1.f / (1.f + __expf(-x)); }

__device__ __forceinline__ void gload16(const void* g, void* l) {
  __builtin_amdgcn_global_load_lds((const __attribute__((address_space(1))) void*)g,
                                   (__attribute__((address_space(3))) void*)l, 16, 0, 0);
}

// ---- Wc (permuted) + fused bias + bf16 W_e copy
__global__ void k_wcat(const float* __restrict__ W_ih, const float* __restrict__ W_hh,
                       const float* __restrict__ b_ih, const float* __restrict__ b_hh,
                       const float* __restrict__ W_e,
                       unsigned short* __restrict__ Wc, float* __restrict__ bsum,
                       unsigned short* __restrict__ Web) {
  int i = blockIdx.x * 256 + threadIdx.x;
  if (i < GD * KX) {
    int mp = i / KX, k = i - mp * KX;
    int nb = mp >> 6, rem = mp & 63, g = rem >> 4, q = rem & 15;
    int mo = g * 256 + nb * 16 + q;
    float v = (k < 576) ? W_ih[mo * 576 + k] : W_hh[mo * 256 + (k - 576)];
    Wc[i] = f2bf(v);
  } else if (i < GD * KX + GD) {
    int j = i - GD * KX;
    int nb = j >> 6, rem = j & 63, g = rem >> 4, q = rem & 15;
    int mo = g * 256 + nb * 16 + q;
    bsum[j] = b_ih[mo] + b_hh[mo];
  } else if (i < GD * KX + GD + ES * HS) {
    int j2 = i - GD * KX - GD;
    Web[j2] = f2bf(W_e[j2]);
  }
}

// ---- collapsed head: Whead[o][320] = (Wo @ W_p2) @ W_p   (5 blocks x 320 thr)
__global__ __launch_bounds__(320) void k_head(
    const float* __restrict__ W_p, const float* __restrict__ b_p,
    const float* __restrict__ W_p2, const float* __restrict__ b_p2,
    const float* __restrict__ W_mu, const float* __restrict__ b_mu,
    const float* __restrict__ W_sd, const float* __restrict__ b_sd,
    const float* __restrict__ W_cr, const float* __restrict__ b_cr,
    float* __restrict__ Whead, float* __restrict__ bhead) {
  int o = blockIdx.x, tid = threadIdx.x;
  __shared__ float to[64];
  const float* Wo = (o < 2) ? W_mu + o * 32 : (o < 4) ? W_sd + (o - 2) * 32 : W_cr;
  if (tid < 64) {
    float a = 0.f;
    #pragma unroll 8
    for (int c = 0; c < 32; ++c) a += Wo[c] * W_p2[c * 64 + tid];
    to[tid] = a;
  }
  __syncthreads();
  float a = 0.f;
  #pragma unroll 8
  for (int j = 0; j < 64; ++j) a += to[j] * W_p[j * 320 + tid];
  Whead[o * 320 + tid] = a;
  if (tid == 0) {
    float b0 = (o < 2) ? b_mu[o] : (o < 4) ? b_sd[o - 2] : b_cr[0];
    float acc = b0;
    for (int c = 0; c < 32; ++c) acc += Wo[c] * b_p2[c];
    for (int j = 0; j < 64; ++j) acc += to[j] * b_p[j];
    bhead[o] = acc;
  }
}

// ---- head for step ts, rows n0..n0+(threads/32). h2(ts) = bf16 h-part of Xh.
__device__ __forceinline__ void head_fin_dev(
    const float* __restrict__ data, const float* __restrict__ W_r,
    const float* __restrict__ b_r, const float* __restrict__ Whead,
    const float* __restrict__ bhead, const unsigned short* __restrict__ Xh,
    float* __restrict__ out, int n0, int ts, int tid) {
  int r8 = tid >> 5, ln = tid & 31;
  int n = n0 + r8;
  float s0 = 0.f, s1 = 0.f, s2 = 0.f, s3 = 0.f, s4 = 0.f;
  u16x8 hv = *(const u16x8*)(Xh + (size_t)n * KX + 576 + ln * 8);
  float hf[8];
  #pragma unroll
  for (int k = 0; k < 8; ++k) hf[k] = bf2f(hv[k]);
  #pragma unroll
  for (int k = 0; k < 8; ++k) {
    int kk = 64 + ln * 8 + k;
    s0 += hf[k] * Whead[0 * 320 + kk];
    s1 += hf[k] * Whead[1 * 320 + kk];
    s2 += hf[k] * Whead[2 * 320 + kk];
    s3 += hf[k] * Whead[3 * 320 + kk];
    s4 += hf[k] * Whead[4 * 320 + kk];
  }
  float x0 = data[(n * T_ + ts) * 2 + 0];
  float x1 = data[(n * T_ + ts) * 2 + 1];
  #pragma unroll
  for (int l2 = 0; l2 < 2; ++l2) {
    int l = ln + 32 * l2;
    float rv = fmaxf(x0 * W_r[l * 2] + x1 * W_r[l * 2 + 1] + b_r[l], 0.f);
    s0 += rv * Whead[0 * 320 + l];
    s1 += rv * Whead[1 * 320 + l];
    s2 += rv * Whead[2 * 320 + l];
    s3 += rv * Whead[3 * 320 + l];
    s4 += rv * Whead[4 * 320 + l];
  }
  #pragma unroll
  for (int off = 16; off; off >>= 1) {
    s0 += __shfl_xor(s0, off);
    s1 += __shfl_xor(s1, off);
    s2 += __shfl_xor(s2, off);
    s3 += __shfl_xor(s3, off);
    s4 += __shfl_xor(s4, off);
  }
  if (ln == 0) {
    out[(n * T_ + ts) * 2 + 0] = s0 + bhead[0];
    out[(n * T_ + ts) * 2 + 1] = s1 + bhead[1];
    out[N_ * T_ * 2 + (n * T_ + ts) * 2 + 0] = __expf(s2 + bhead[2]);
    out[N_ * T_ * 2 + (n * T_ + ts) * 2 + 1] = __expf(s3 + bhead[3]);
    out[N_ * T_ * 4 + n * T_ + ts] = tanhf(s4 + bhead[4]);
  }
}

// ---- social (256 blocks x 512 thr; block = (b, ig8) owning 16 rows)
__global__ __launch_bounds__(512) void k_social(
    const float* __restrict__ data, const unsigned short* __restrict__ Web,
    const float* __restrict__ b_e, unsigned short* __restrict__ Xcur,
    const float* __restrict__ Whead, const float* __restrict__ bhead,
    const float* __restrict__ W_r, const float* __restrict__ b_r,
    float* __restrict__ out, int t) {
  int b   = blockIdx.x >> 3;
  int ig8 = blockIdx.x & 7;
  int n0  = b * A_ + ig8 * 16;
  __shared__ float sx[A_], sy[A_];
  __shared__ float shw2[64 * 64];       // [jp][c][sub]  16 KB
  __shared__ float smx[16][64][8];      // 32 KB
  __shared__ float smy[16][64][8];      // 32 KB
  int tid = threadIdx.x;
  if (tid < A_) {
    sx[tid] = data[((b * A_ + tid) * T_ + t) * 2 + 0];
    sy[tid] = data[((b * A_ + tid) * T_ + t) * 2 + 1];
  }
  if (t > 0)
    head_fin_dev(data, W_r, b_r, Whead, bhead, Xcur, out, n0, t - 1, tid);
  for (int u = tid; u < 1024; u += 512) {
    int rr = u >> 6, l = u & 63;
    int n = n0 + rr;
    float x0 = data[(n * T_ + t) * 2 + 0];
    float x1 = data[(n * T_ + t) * 2 + 1];
    Xcur[(size_t)n * KX + l] =
        f2bf(fmaxf(x0 * W_r[l * 2] + x1 * W_r[l * 2 + 1] + b_r[l], 0.f));
  }
  if (t == 0) {
    for (int i = tid; i < 64 * 64; i += 512) shw2[i] = 0.f;
    u16x8 z = (u16x8){0, 0, 0, 0, 0, 0, 0, 0};
    int row = tid >> 5, c8 = tid & 31;
    *(u16x8*)(Xcur + (size_t)(n0 + row) * KX + 576 + c8 * 8) = z;
  } else {
    int w = tid >> 6, lane = tid & 63;
    int lr = lane & 15, lh = lane >> 4;
    const unsigned short* a0p = Xcur + (size_t)(b * A_ + w * 16 + lr) * KX + 576 + lh * 8;
    const unsigned short* b0p = Web + lr * HS + lh * 8;
    const unsigned short* b1p = Web + (16 + lr) * HS + lh * 8;
    f4_t hacc[2];
    hacc[0] = (f4_t){0.f, 0.f, 0.f, 0.f}; hacc[1] = hacc[0];
    #pragma unroll
    for (int kk = 0; kk < 8; ++kk) {
      bf8_t av  = *(const bf8_t*)(a0p + kk * 32);
      bf8_t bv0 = *(const bf8_t*)(b0p + kk * 32);
      bf8_t bv1 = *(const bf8_t*)(b1p + kk * 32);
      hacc[0] = __builtin_amdgcn_mfma_f32_16x16x32_bf16(av, bv0, hacc[0], 0, 0, 0);
      hacc[1] = __builtin_amdgcn_mfma_f32_16x16x32_bf16(av, bv1, hacc[1], 0, 0, 0);
    }
    int ccol = lane & 15, crow4 = (lane >> 4) * 4;
    #pragma unroll
    for (int cb2 = 0; cb2 < 2; ++cb2)
      #pragma unroll
      for (int j = 0; j < 4; ++j) {
        int rr = w * 16 + crow4 + j;
        int c  = cb2 * 16 + ccol;
        shw2[(rr >> 1) * 64 + c * 2 + (rr & 1)] = hacc[cb2][j];
      }
  }
  __syncthreads();

  for (int u = tid; u < 1024; u += 512) {
    int r = u >> 6, jp = u & 63;
    int irow = ig8 * 16 + r;
    float xi = sx[irow], yi = sy[irow];
    bool acti = xi >= 0.f;
    float m0[4], m1[4], nn0[4], nn1[4];
    #pragma unroll
    for (int s = 0; s < 2; ++s) {
      int j = jp * 2 + s;
      float xj = sx[j], yj = sy[j];
      bool v = acti && (xj >= 0.f) && (j != irow);
      float dx = xi - xj, dy = yi - yj;
      float* mm = s ? m1 : m0;
      float* nn = s ? nn1 : nn0;
      mm[0] = (v && dx >= 8.f   && dx <= 16.f) ? 1.f : 0.f;
      mm[1] = (v && dx >= 0.f   && dx <= 8.f ) ? 1.f : 0.f;
      mm[2] = (v && dx >= -8.f  && dx <= 0.f ) ? 1.f : 0.f;
      mm[3] = (v && dx >= -16.f && dx <= -8.f) ? 1.f : 0.f;
      nn[0] = (dy >= -16.f && dy <= -8.f) ? 1.f : 0.f;
      nn[1] = (dy >= -8.f  && dy <= 0.f ) ? 1.f : 0.f;
      nn[2] = (dy >= 0.f   && dy <= 8.f ) ? 1.f : 0.f;
      nn[3] = (dy >= 8.f   && dy <= 16.f) ? 1.f : 0.f;
    }
    float4* px = (float4*)&smx[r][jp][0];
    px[0] = (float4){m0[0], m1[0], m0[1], m1[1]};
    px[1] = (float4){m0[2], m1[2], m0[3], m1[3]};
    float4* py = (float4*)&smy[r][jp][0];
    py[0] = (float4){nn0[0], nn1[0], nn0[1], nn1[1]};
    py[1] = (float4){nn0[2], nn1[2], nn0[3], nn1[3]};
  }
  __syncthreads();

  int half = tid >> 5;               // row 0..15
  int lane = tid & 31;               // channel
  f2_t acc[16];
  #pragma unroll
  for (int g = 0; g < 16; ++g) acc[g] = (f2_t){0.f, 0.f};
  #pragma unroll 2
  for (int jp = 0; jp < 64; ++jp) {
    f2_t hv = *(const f2_t*)&shw2[jp * 64 + lane * 2];
    float4 xa = ((const float4*)&smx[half][jp][0])[0];
    float4 xb = ((const float4*)&smx[half][jp][0])[1];
    float4 ya = ((const float4*)&smy[half][jp][0])[0];
    float4 yb = ((const float4*)&smy[half][jp][0])[1];
    f2_t mx[4] = {(f2_t){xa.x, xa.y}, (f2_t){xa.z, xa.w},
                  (f2_t){xb.x, xb.y}, (f2_t){xb.z, xb.w}};
    f2_t p[4]  = {(f2_t){ya.x, ya.y} * hv, (f2_t){ya.z, ya.w} * hv,
                  (f2_t){yb.x, yb.y} * hv, (f2_t){yb.z, yb.w} * hv};
    #pragma unroll
    for (int gy = 0; gy < 4; ++gy)
      #pragma unroll
      for (int gx = 0; gx < 4; ++gx)
        acc[gy * 4 + gx] += mx[gx] * p[gy];
  }

  int irow = ig8 * 16 + half;
  float be = b_e[lane];
  int hi = irow >> 4;                // == ig8
  int klo = (irow & 15) * ES + lane;
  #pragma unroll
  for (int g = 0; g < 16; ++g) {
    float e = fmaxf(acc[g][0] + acc[g][1] + be, 0.f);
    int a_out = g * 8 + hi;
    Xcur[(size_t)(b * A_ + a_out) * KX + 64 + klo] = f2bf(e);
  }
}

// ---- gates GEMM + register-direct LSTM pointwise.
// BM=128, BN=128, BK=32, 512 thr. 4-buffer rotation, counted vmcnt(2),
// raw s_barrier (one per stage, loads stay in flight across barriers).
__global__ __launch_bounds__(512) void k_gemm_lstm(
    const unsigned short* __restrict__ Xcur, const unsigned short* __restrict__ Wc,
    const float* __restrict__ bsum,
    float* __restrict__ cbuf, unsigned short* __restrict__ Xnext, int t) {
  __shared__ unsigned short sA0[128 * 32], sB0[128 * 32];   // 8 KB each
  __shared__ unsigned short sA1[128 * 32], sB1[128 * 32];
  __shared__ unsigned short sA2[128 * 32], sB2[128 * 32];
  __shared__ unsigned short sA3[128 * 32], sB3[128 * 32];   // total 64 KB

  int bid = blockIdx.x;
  int tm = bid & 31, tc = bid >> 5;
  int row0 = tm * 128, col0 = tc * 128;
  int tid = threadIdx.x;
  int lane = tid & 63;
  int w = tid >> 6;
  int wr = w >> 1, wc = w & 1;              // 8 waves: 32 rows x 64 cols each
  int lr = lane & 15, lh = lane >> 4;

  // staging: thread -> (row tid>>2, chunk tid&3); global chunk pre-swizzled
  int srow = tid >> 2, schunk = tid & 3;
  int gch = (schunk ^ ((srow >> 1) & 3)) * 8;
  const unsigned short* gA = Xcur + (size_t)(row0 + srow) * KX + gch;
  const unsigned short* gB = Wc  + (size_t)(col0 + srow) * KX + gch;

  int swz = (lh ^ ((lr >> 1) & 3)) * 8;
  int aoff[2], boff[4];
  #pragma unroll
  for (int m = 0; m < 2; ++m) aoff[m] = (wr * 32 + m * 16 + lr) * 32 + swz;
  #pragma unroll
  for (int n = 0; n < 4; ++n) boff[n] = (wc * 64 + n * 16 + lr) * 32 + swz;

  f4_t acc[2][4];
  #pragma unroll
  for (int m = 0; m < 2; ++m)
    #pragma unroll
    for (int n = 0; n < 4; ++n) acc[m][n] = (f4_t){0.f, 0.f, 0.f, 0.f};

#define STAGE(pA, pB, kt) do { \
    gload16(gA + (size_t)(kt) * 32, (pA) + tid * 8); \
    gload16(gB + (size_t)(kt) * 32, (pB) + tid * 8); \
  } while (0)

#define COMPUTE(pA, pB) do { \
    bf8_t a_[2], b_[4]; \
    _Pragma("unroll") for (int m = 0; m < 2; ++m) a_[m] = *(const bf8_t*)((pA) + aoff[m]); \
    _Pragma("unroll") for (int n = 0; n < 4; ++n) b_[n] = *(const bf8_t*)((pB) + boff[n]); \
    _Pragma("unroll") for (int m = 0; m < 2; ++m) \
      _Pragma("unroll") for (int n = 0; n < 4; ++n) \
        acc[m][n] = __builtin_amdgcn_mfma_f32_16x16x32_bf16(a_[m], b_[n], acc[m][n], 0, 0, 0); \
  } while (0)

// one pipeline step: stage kt ready (vmcnt(2): kt+1 stays in flight),
// prefetch kt+2 into the buffer freed at kt-2, compute kt.
#define ITER(AC, BC, AN, BN, kt) do { \
    asm volatile("s_waitcnt vmcnt(2)" ::: "memory"); \
    __builtin_amdgcn_sched_barrier(0); \
    __builtin_amdgcn_s_barrier(); \
    STAGE(AN, BN, (kt) + 2); \
    COMPUTE(AC, BC); \
  } while (0)

  STAGE(sA0, sB0, 0);
  STAGE(sA1, sB1, 1);
  #pragma unroll 1
  for (int kt = 0; kt < 24; kt += 4) {
    ITER(sA0, sB0, sA2, sB2, kt);
    ITER(sA1, sB1, sA3, sB3, kt + 1);
    ITER(sA2, sB2, sA0, sB0, kt + 2);
    ITER(sA3, sB3, sA1, sB1, kt + 3);
  }
  // kt = 24: stage ready via vmcnt(2) (only 25 in flight behind it), no prefetch
  asm volatile("s_waitcnt vmcnt(2)" ::: "memory");
  __builtin_amdgcn_sched_barrier(0);
  __builtin_amdgcn_s_barrier();
  COMPUTE(sA0, sB0);
  // kt = 25: last stage, drain fully
  asm volatile("s_waitcnt vmcnt(0)" ::: "memory");
  __builtin_amdgcn_sched_barrier(0);
  __builtin_amdgcn_s_barrier();
  COMPUTE(sA1, sB1);
#undef ITER
#undef STAGE
#undef COMPUTE

  // register-direct LSTM pointwise
  int q = lane & 15;
  float bias_g[4];
  #pragma unroll
  for (int n = 0; n < 4; ++n) bias_g[n] = bsum[col0 + wc * 64 + n * 16 + q];
  int ch = (tc * 2 + wc) * 16 + q;
  int jrow4 = (lane >> 4) * 4;
  #pragma unroll
  for (int m = 0; m < 2; ++m) {
    #pragma unroll
    for (int j = 0; j < 4; ++j) {
      int row = row0 + wr * 32 + m * 16 + jrow4 + j;
      float ig = acc[m][0][j] + bias_g[0];
      float fg = acc[m][1][j] + bias_g[1];
      float gg = acc[m][2][j] + bias_g[2];
      float og = acc[m][3][j] + bias_g[3];
      float cold = (t == 0) ? 0.f : cbuf[(size_t)row * HS + ch];
      float c2 = sigm(fg) * cold + sigm(ig) * tanhf(gg);
      float h2 = sigm(og) * tanhf(c2);
      cbuf[(size_t)row * HS + ch] = c2;
      Xnext[(size_t)row * KX + 576 + ch] = f2bf(h2);
    }
  }
}

// ---- final head for t=63 (512 blocks x 8 rows); Xh = X holding h2(63)
__global__ __launch_bounds__(256) void k_fin(
    const float* __restrict__ data, const float* __restrict__ W_r,
    const float* __restrict__ b_r, const float* __restrict__ Whead,
    const float* __restrict__ bhead, const unsigned short* __restrict__ Xh,
    float* __restrict__ out) {
  head_fin_dev(data, W_r, b_r, Whead, bhead, Xh, out,
               blockIdx.x * 8, T_ - 1, threadIdx.x);
}

extern "C" void kernel_launch(void* const* d_in, const int* in_sizes, int n_in,
                              void* d_out, int out_size, void* d_ws, size_t ws_size,
                              hipStream_t stream) {
  const float* data = (const float*)d_in[0];
  const float* W_r  = (const float*)d_in[2];
  const float* b_r  = (const float*)d_in[3];
  const float* W_e  = (const float*)d_in[4];
  const float* b_e  = (const float*)d_in[5];
  const float* W_ih = (const float*)d_in[6];
  const float* W_hh = (const float*)d_in[7];
  const float* b_ih = (const float*)d_in[8];
  const float* b_hh = (const float*)d_in[9];
  const float* W_p  = (const float*)d_in[10];
  const float* b_p  = (const float*)d_in[11];
  const float* W_p2 = (const float*)d_in[12];
  const float* b_p2 = (const float*)d_in[13];
  const float* W_mu = (const float*)d_in[14];
  const float* b_mu = (const float*)d_in[15];
  const float* W_sd = (const float*)d_in[16];
  const float* b_sd = (const float*)d_in[17];
  const float* W_cr = (const float*)d_in[18];
  const float* b_cr = (const float*)d_in[19];
  float* out = (float*)d_out;

  char* ws = (char*)d_ws;
  float* cbuf  = (float*)(ws);                                // 4 MB
  unsigned short* Xbf0 = (unsigned short*)(ws + (4u  << 20)); // 6.5 MB
  unsigned short* Xbf1 = (unsigned short*)(ws + (11u << 20)); // 6.5 MB
  unsigned short* Wc   = (unsigned short*)(ws + (18u << 20)); // 1.7 MB
  float* bsum  = (float*)(ws + (20u << 20));                  // 4 KB
  float* Whead = (float*)(ws + (20u << 20) + 8192);           // 6.4 KB
  float* bhead = (float*)(ws + (20u << 20) + 16384);          // 20 B
  unsigned short* Web = (unsigned short*)(ws + (20u << 20) + 20480); // 16 KB

  k_wcat<<<(GD * KX + GD + ES * HS + 255) / 256, 256, 0, stream>>>(
      W_ih, W_hh, b_ih, b_hh, W_e, Wc, bsum, Web);
  k_head<<<5, 320, 0, stream>>>(W_p, b_p, W_p2, b_p2, W_mu, b_mu, W_sd, b_sd, W_cr, b_cr,
                                Whead, bhead);

  for (int t = 0; t < T_; ++t) {
    unsigned short* Xcur  = (t & 1) ? Xbf1 : Xbf0;
    unsigned short* Xnext = (t & 1) ? Xbf0 : Xbf1;
    k_social<<<256, 512, 0, stream>>>(data, Web, b_e, Xcur, Whead, bhead,
                                      W_r, b_r, out, t);
    k_gemm_lstm<<<256, 512, 0, stream>>>(Xcur, Wc, bsum, cbuf, Xnext, t);
  }
  // h2(63) lives in Xnext of t=63 -> Xbf0 (t=63 odd)
  k_fin<<<512, 256, 0, stream>>>(data, W_r, b_r, Whead, bhead, Xbf0, out);
}